// Round 19
// baseline (575.000 us; speedup 1.0000x reference)
//
#include <hip/hip_runtime.h>

typedef unsigned short u16;
typedef unsigned int u32;
typedef float f32x4 __attribute__((ext_vector_type(4)));
typedef u32 u32x2 __attribute__((ext_vector_type(2)));
typedef __bf16 bf16x8 __attribute__((ext_vector_type(8)));

#define DEV __device__ __forceinline__

DEV u16 f2b(float f) {
    union { float f; u32 u; } v; v.f = f;
    u32 r = v.u + 0x7fffu + ((v.u >> 16) & 1u);   // RNE
    return (u16)(r >> 16);
}
DEV float b2f(u16 b) {
    union { u32 u; float f; } v; v.u = ((u32)b) << 16;
    return v.f;
}

// global -> LDS direct (16B/lane). LDS dest must be wave-uniform base; HW adds lane*16.
DEV void gload16(const void* g, void* l) {
    __builtin_amdgcn_global_load_lds((const __attribute__((address_space(1))) void*)g,
                                     (__attribute__((address_space(3))) void*)l, 16, 0, 0);
}

DEV f32x4 mfma16(bf16x8 a, bf16x8 b, f32x4 c) {
    return __builtin_amdgcn_mfma_f32_16x16x32_bf16(a, b, c, 0, 0, 0);
}

// -------------- merged pre-GEMM pass: convx ∥ tconv3(wq,wk,wv).
// Both outputs (xb, fBt) are exactly the QKV GEMM's operands — no unrelated working set
// is introduced before the GEMM (r16 lesson: 96 MB of unrelated traffic before the GEMM
// evicted xb/fBt and cost 7% on the GEMM).
__global__ __launch_bounds__(256) void pre_kernel(const float* __restrict__ x,
                                                  const float* __restrict__ wq,
                                                  const float* __restrict__ wk,
                                                  const float* __restrict__ wv,
                                                  u16* __restrict__ xb,
                                                  u16* __restrict__ fBt) {
    int id = blockIdx.x;
    int t = threadIdx.x;
    if (id < 16384) {
        // ---- convx
        size_t i = ((size_t)id * 256 + t) * 4;
        float4 v = *(const float4*)(x + i);
        ushort4 o; o.x = f2b(v.x); o.y = f2b(v.y); o.z = f2b(v.z); o.w = f2b(v.w);
        *(ushort4*)(xb + i) = o;
        return;
    }
    // ---- tconv3: i0 -> (bx = i0 % 96, ky = i0 / 96)
    __shared__ float tile[64][65];
    int i0 = id - 16384;
    int n0 = (i0 % 96) * 64, k0 = (i0 / 96) * 64;
    const float* src; int Ns, nl;
    if (n0 < 4096)      { src = wq; Ns = 4096; nl = n0; }
    else if (n0 < 5120) { src = wk; Ns = 1024; nl = n0 - 4096; }
    else                { src = wv; Ns = 1024; nl = n0 - 5120; }
    int r = t >> 4, c4 = (t & 15) * 4;
#pragma unroll
    for (int i = 0; i < 4; ++i) {
        float4 v = *(const float4*)(src + (size_t)(k0 + i * 16 + r) * Ns + nl + c4);
        tile[i * 16 + r][c4 + 0] = v.x; tile[i * 16 + r][c4 + 1] = v.y;
        tile[i * 16 + r][c4 + 2] = v.z; tile[i * 16 + r][c4 + 3] = v.w;
    }
    __syncthreads();
#pragma unroll
    for (int i = 0; i < 4; ++i) {
        int nn = i * 16 + r;
        ushort4 o;
        o.x = f2b(tile[c4 + 0][nn]); o.y = f2b(tile[c4 + 1][nn]);
        o.z = f2b(tile[c4 + 2][nn]); o.w = f2b(tile[c4 + 3][nn]);
        *(ushort4*)(fBt + (size_t)(n0 + nn) * 4096 + k0 + c4) = o;
    }
}

// ----------------------- 128x128 2-phase GEMM body (r10/r13/r17 measured-best: 43%
// MfmaUtil, 2 independent blocks/CU, LDS 64 KiB; ~90-95% of this data path's LDS-BW
// structural bound. Six geometry/schedule variants (r3-r6, r12, r14) all worse.)
#define GEMM128_BODY                                                                        \
    __shared__ __align__(16) u16 Asb[2][2][64 * 64];                                        \
    __shared__ __align__(16) u16 Bsb[2][2][64 * 64];                                        \
    int t = threadIdx.x;                                                                    \
    int lane = t & 63, w = t >> 6;                                                          \
    int wrM = w >> 1, wcN = w & 1;                                                          \
    int lr = lane & 15, hi = lane >> 4;                                                     \
    int wg = blockIdx.x;                                                                    \
    int swz = (wg & 7) * ((int)gridDim.x >> 3) + (wg >> 3);                                 \
    int bx = swz / gy, by = swz % gy;                                                       \
    int m0 = by * 128, n0 = bx * 128;                                                       \
    int nk = K >> 6;                                                                        \
    auto stageA = [&](int X, int h) {                                                       \
        const u16* src = A + (size_t)(m0 + h * 64) * K + X * 64;                            \
        char* dst = (char*)&Asb[X & 1][h][0];                                               \
        _Pragma("unroll")                                                                   \
        for (int it = 0; it < 2; ++it) {                                                    \
            int c = it * 256 + t;                                                           \
            int row = c >> 3;                                                               \
            int col8 = ((c & 7) ^ (row & 7)) << 3;                                          \
            gload16(src + (size_t)row * K + col8, dst + (it * 256 + (t & ~63)) * 16);       \
        }                                                                                   \
    };                                                                                      \
    auto stageB = [&](int X, int h) {                                                       \
        const u16* src = Bt + (size_t)(n0 + h * 64) * K + X * 64;                           \
        char* dst = (char*)&Bsb[X & 1][h][0];                                               \
        _Pragma("unroll")                                                                   \
        for (int it = 0; it < 2; ++it) {                                                    \
            int c = it * 256 + t;                                                           \
            int row = c >> 3;                                                               \
            int col8 = ((c & 7) ^ (row & 7)) << 3;                                          \
            gload16(src + (size_t)row * K + col8, dst + (it * 256 + (t & ~63)) * 16);       \
        }                                                                                   \
    };                                                                                      \
    stageA(0, 0); stageA(0, 1); stageB(0, 0); stageB(0, 1);                                 \
    stageA(1, 0); stageA(1, 1);                                                             \
    asm volatile("s_waitcnt vmcnt(4)" ::: "memory");                                        \
    __builtin_amdgcn_s_barrier();                                                           \
    f32x4 acc[4][4] = {};                                                                   \
    for (int kt = 0; kt < nk; ++kt) {                                                       \
        __builtin_amdgcn_sched_barrier(0);                                                  \
        int p = kt & 1;                                                                     \
        const char* Ah = (const char*)&Asb[p][wrM][0];                                      \
        const char* Bh = (const char*)&Bsb[p][wcN][0];                                      \
        bool s1 = (kt + 1 < nk), s2 = (kt + 2 < nk);                                        \
        bf16x8 a[4][2], bb[2][2];                                                           \
        _Pragma("unroll")                                                                   \
        for (int mf = 0; mf < 4; ++mf)                                                      \
            _Pragma("unroll")                                                               \
            for (int ks = 0; ks < 2; ++ks) {                                                \
                int row = mf * 16 + lr;                                                     \
                a[mf][ks] = *(const bf16x8*)(Ah + ((row * 128 + ks * 64 + hi * 16) ^ ((row & 7) << 4))); \
            }                                                                               \
        _Pragma("unroll")                                                                   \
        for (int nf = 0; nf < 2; ++nf)                                                      \
            _Pragma("unroll")                                                               \
            for (int ks = 0; ks < 2; ++ks) {                                                \
                int row = nf * 16 + lr;                                                     \
                bb[nf][ks] = *(const bf16x8*)(Bh + ((row * 128 + ks * 64 + hi * 16) ^ ((row & 7) << 4))); \
            }                                                                               \
        if (s1) { stageB(kt + 1, 0); stageB(kt + 1, 1); }                                   \
        __builtin_amdgcn_s_barrier();                                                       \
        __builtin_amdgcn_s_setprio(1);                                                      \
        _Pragma("unroll")                                                                   \
        for (int mf = 0; mf < 4; ++mf)                                                      \
            _Pragma("unroll")                                                               \
            for (int nf = 0; nf < 2; ++nf)                                                  \
                _Pragma("unroll")                                                           \
                for (int ks = 0; ks < 2; ++ks)                                              \
                    acc[mf][nf] = mfma16(a[mf][ks], bb[nf][ks], acc[mf][nf]);               \
        __builtin_amdgcn_s_setprio(0);                                                      \
        __builtin_amdgcn_s_barrier();                                                       \
        _Pragma("unroll")                                                                   \
        for (int nf = 0; nf < 2; ++nf)                                                      \
            _Pragma("unroll")                                                               \
            for (int ks = 0; ks < 2; ++ks) {                                                \
                int row = (nf + 2) * 16 + lr;                                               \
                bb[nf][ks] = *(const bf16x8*)(Bh + ((row * 128 + ks * 64 + hi * 16) ^ ((row & 7) << 4))); \
            }                                                                               \
        if (s2) { stageA(kt + 2, 0); stageA(kt + 2, 1); }                                   \
        __builtin_amdgcn_s_barrier();                                                       \
        __builtin_amdgcn_s_setprio(1);                                                      \
        _Pragma("unroll")                                                                   \
        for (int mf = 0; mf < 4; ++mf)                                                      \
            _Pragma("unroll")                                                               \
            for (int nf = 0; nf < 2; ++nf)                                                  \
                _Pragma("unroll")                                                           \
                for (int ks = 0; ks < 2; ++ks)                                              \
                    acc[mf][nf + 2] = mfma16(a[mf][ks], bb[nf][ks], acc[mf][nf + 2]);       \
        __builtin_amdgcn_s_setprio(0);                                                      \
        if (s2)      asm volatile("s_waitcnt vmcnt(4)" ::: "memory");                       \
        else if (s1) asm volatile("s_waitcnt vmcnt(0)" ::: "memory");                       \
        __builtin_amdgcn_s_barrier();                                                       \
    }

// ------------------- bf16-out 128x128 GEMM (QKV projection)
__global__ __launch_bounds__(256, 2) void gemm128_bf16_kernel(const u16* __restrict__ A,
                                                              const u16* __restrict__ Bt,
                                                              u16* __restrict__ Cb,
                                                              int N, int K, int gy) {
    GEMM128_BODY
#pragma unroll
    for (int mf = 0; mf < 4; ++mf)
#pragma unroll
        for (int nf = 0; nf < 4; ++nf)
#pragma unroll
            for (int r = 0; r < 4; ++r) {
                int m = m0 + wrM * 64 + mf * 16 + hi * 4 + r;
                int n = n0 + wcN * 64 + nf * 16 + lr;
                Cb[(size_t)m * N + n] = f2b(acc[mf][nf][r]);
            }
}

// ------------------- f32-out 128x128 GEMM (WO projection)
__global__ __launch_bounds__(256, 2) void gemm128_f32_kernel(const u16* __restrict__ A,
                                                             const u16* __restrict__ Bt,
                                                             float* __restrict__ Cf,
                                                             int N, int K, int gy) {
    GEMM128_BODY
#pragma unroll
    for (int mf = 0; mf < 4; ++mf)
#pragma unroll
        for (int nf = 0; nf < 4; ++nf)
#pragma unroll
            for (int r = 0; r < 4; ++r) {
                int m = m0 + wrM * 64 + mf * 16 + hi * 4 + r;
                int n = n0 + wcN * 64 + nf * 16 + lr;
                Cf[(size_t)m * N + n] = acc[mf][nf][r];
            }
}

// -------------- merged post-QKV pass: RoPE(q pre-scaled, k + outk f32 x4) ∥ V-transpose
// ∥ tconv(wo). All three run between the QKV GEMM and their consumers (r16 cache lesson).
// q pre-scale now includes log2(e): QK^T emerges in the log2 domain so attention's
// softmax uses raw v_exp_f32 (exp2f) with no per-element multiply.
__global__ __launch_bounds__(256) void postproc_kernel(u16* __restrict__ qkv,
                                                       float* __restrict__ outk,
                                                       u16* __restrict__ vt,
                                                       float* __restrict__ outv,
                                                       const float* __restrict__ wo,
                                                       u16* __restrict__ wob) {
    int id = blockIdx.x;
    int tid = threadIdx.x;
    if (id < 40960) {
        // ---- RoPE: id -> (bx = id%10, row = id/10)
        int row = id / 10;
        int p = (id % 10) * 256 + tid;
        int b = row >> 11, l = row & 2047;
        float freq = exp2f((float)(p & 63) * -0.2076205059304601f);  // 10000^(-i/64)
        float sv, cv; sincosf((float)l * freq, &sv, &cv);
        if (p < 2048) {
            // (1/sqrt(128)) * log2(e) folded into q -> scores in log2 domain
            const float SC = 0.08838834764831845f * 1.4426950408889634f;
            int h = p >> 6, i = p & 63;
            size_t idx = (size_t)row * 6144 + h * 128 + 2 * i;
            u32 pr = *(const u32*)(qkv + idx);
            float x1 = b2f((u16)(pr & 0xffff)), x2 = b2f((u16)(pr >> 16));
            float o1 = (x1 * cv + x2 * sv) * SC, o2 = (x1 * sv - x2 * cv) * SC;
            *(u32*)(qkv + idx) = (u32)f2b(o1) | ((u32)f2b(o2) << 16);
        } else {
            int kvh = (p >> 6) - 32, i = p & 63;
            size_t idx = (size_t)row * 6144 + 4096 + kvh * 128 + 2 * i;
            u32 pr = *(const u32*)(qkv + idx);
            float x1 = b2f((u16)(pr & 0xffff)), x2 = b2f((u16)(pr >> 16));
            float o1 = x1 * cv + x2 * sv, o2 = x1 * sv - x2 * cv;
            *(u32*)(qkv + idx) = (u32)f2b(o1) | ((u32)f2b(o2) << 16);
#pragma unroll
            for (int r = 0; r < 4; ++r) {
                float2 o; o.x = o1; o.y = o2;
                *(float2*)(outk + ((size_t)((b * 32 + kvh * 4 + r) * 2048) + l) * 128 + 2 * i) = o;
            }
        }
        return;
    }
    __shared__ u16 tile16[64][65];
    __shared__ float tile32[64][65];
    if (id < 41984) {
        // ---- V transpose
        int i0 = id - 40960;
        int l0 = (i0 & 31) * 64, d0 = ((i0 >> 5) & 1) * 64;
        int z = i0 >> 6, b = z >> 3, kvh = z & 7;
        int r = tid >> 4, c4 = (tid & 15) * 4;
#pragma unroll
        for (int i = 0; i < 4; ++i) {
            int l = l0 + i * 16 + r;
            ushort4 v = *(const ushort4*)(qkv + (size_t)(b * 2048 + l) * 6144 + 5120 + kvh * 128 + d0 + c4);
            tile16[i * 16 + r][c4 + 0] = v.x; tile16[i * 16 + r][c4 + 1] = v.y;
            tile16[i * 16 + r][c4 + 2] = v.z; tile16[i * 16 + r][c4 + 3] = v.w;
            float4 f; f.x = b2f(v.x); f.y = b2f(v.y); f.z = b2f(v.z); f.w = b2f(v.w);
#pragma unroll
            for (int rr = 0; rr < 4; ++rr)
                *(float4*)(outv + ((size_t)((b * 32 + kvh * 4 + rr) * 2048) + l) * 128 + d0 + c4) = f;
        }
        __syncthreads();
#pragma unroll
        for (int i = 0; i < 4; ++i) {
            int dn = i * 16 + r;
            ushort4 o;
            o.x = tile16[c4 + 0][dn]; o.y = tile16[c4 + 1][dn];
            o.z = tile16[c4 + 2][dn]; o.w = tile16[c4 + 3][dn];
            *(ushort4*)(vt + (size_t)((b * 8 + kvh) * 128 + d0 + dn) * 2048 + l0 + c4) = o;
        }
    } else {
        // ---- tconv(wo): i1 -> (nx = i1 & 63, ky = i1 >> 6)
        int i1 = id - 41984;
        int n0 = (i1 & 63) * 64, k0 = (i1 >> 6) * 64;
        int r = tid >> 4, c4 = (tid & 15) * 4;
#pragma unroll
        for (int i = 0; i < 4; ++i) {
            float4 v = *(const float4*)(wo + (size_t)(k0 + i * 16 + r) * 4096 + n0 + c4);
            tile32[i * 16 + r][c4 + 0] = v.x; tile32[i * 16 + r][c4 + 1] = v.y;
            tile32[i * 16 + r][c4 + 2] = v.z; tile32[i * 16 + r][c4 + 3] = v.w;
        }
        __syncthreads();
#pragma unroll
        for (int i = 0; i < 4; ++i) {
            int nn = i * 16 + r;
            ushort4 o;
            o.x = f2b(tile32[c4 + 0][nn]); o.y = f2b(tile32[c4 + 1][nn]);
            o.z = f2b(tile32[c4 + 2][nn]); o.w = f2b(tile32[c4 + 3][nn]);
            *(ushort4*)(wob + (size_t)(n0 + nn) * 4096 + k0 + c4) = o;
        }
    }
}

// ---------------------------------------------------------------- flash attention v4.3
// v4.2 + exp2 domain: q pre-scaled by (1/sqrt(d))*log2(e), so P = exp2(s - m) directly
// (v_exp_f32 is base-2; deletes 32 v_mul/lane/kv-step). defer-max THR = 8*log2(e).
__global__ __launch_bounds__(256, 2) void attn_kernel(const u16* __restrict__ qkv,
                                                      const u16* __restrict__ vt,
                                                      u16* __restrict__ ab) {
    __shared__ __align__(16) u16 Kbuf[2][64 * 128];   // K tile [kv][dh]     32 KB
    __shared__ __align__(16) u16 Vbuf[2][128 * 64];   // V^T tile [dh][kv]   32 KB
    __shared__ __align__(16) u16 Ps[4][32 * 64];      // per-wave P [q=32][kv=64]  16 KB
    int t = threadIdx.x, lane = t & 63, w = t >> 6;
    int lr = lane & 15, hi = lane >> 4;
    int h = blockIdx.y, b = blockIdx.z, kvh = h >> 2;

    const u16* kbase = qkv + (size_t)(b * 2048) * 6144 + 4096 + kvh * 128;
    const u16* vtbase = vt + (size_t)((b * 8 + kvh) * 128) * 2048;

    auto stageKV = [&](int k0, int buf) {
#pragma unroll
        for (int i = 0; i < 4; ++i) {   // K: 64 rows x 128 cols
            int c = i * 256 + t;
            int row = c >> 4;
            int col8 = ((c & 15) ^ (row & 7)) << 3;
            gload16(kbase + (size_t)(k0 + row) * 6144 + col8,
                    (char*)Kbuf[buf] + (i * 256 + (t & ~63)) * 16);
        }
#pragma unroll
        for (int i = 0; i < 4; ++i) {   // V^T: 128 rows x 64 cols
            int c = i * 256 + t;
            int row = c >> 3;
            int col8 = ((c & 7) ^ (row & 7)) << 3;
            gload16(vtbase + (size_t)row * 2048 + k0 + col8,
                    (char*)Vbuf[buf] + (i * 256 + (t & ~63)) * 16);
        }
    };

    auto process = [&](int qblk) {
        int q0 = qblk * 128;
        bf16x8 qf[2][4];
#pragma unroll
        for (int half = 0; half < 2; ++half)
#pragma unroll
            for (int kki = 0; kki < 4; ++kki)
                qf[half][kki] = *(const bf16x8*)(qkv +
                    (size_t)(b * 2048 + q0 + w * 32 + half * 16 + lr) * 6144 + h * 128 +
                    kki * 32 + 8 * hi);
        f32x4 acc[2][8] = {};
        float mrun[2] = {-1e30f, -1e30f}, lrun[2] = {0.f, 0.f};

        int nt = 2 * (qblk + 1);
        stageKV(0, 0);
        __syncthreads();
        int cur = 0;
        for (int kt = 0; kt < nt; ++kt) {
            if (kt + 1 < nt) stageKV((kt + 1) * 64, cur ^ 1);  // prefetch next tile
            __builtin_amdgcn_sched_barrier(0);

            const u16* Ks = Kbuf[cur];
            const u16* Vs = Vbuf[cur];
            // S^T = K Q^T (scores in log2 domain; q pre-scaled by SC*log2e)
            f32x4 s[2][4] = {};
            __builtin_amdgcn_s_setprio(1);
#pragma unroll
            for (int kki = 0; kki < 4; ++kki) {
                bf16x8 kf[4];
#pragma unroll
                for (int fc = 0; fc < 4; ++fc) {
                    int kvr = fc * 16 + lr;
                    int byt = (kvr * 256 + (kki * 32 + 8 * hi) * 2) ^ ((kvr & 7) << 4);
                    kf[fc] = *(const bf16x8*)((const char*)Ks + byt);
                }
#pragma unroll
                for (int fc = 0; fc < 4; ++fc) {
                    s[0][fc] = mfma16(kf[fc], qf[0][kki], s[0][fc]);
                    s[1][fc] = mfma16(kf[fc], qf[1][kki], s[1][fc]);
                }
            }
            __builtin_amdgcn_s_setprio(0);
            int domask = (kt >= nt - 2);
            u16* Pw = Ps[w];
#pragma unroll
            for (int half = 0; half < 2; ++half) {
                int qabs = q0 + w * 32 + half * 16 + lr;
                if (domask) {
#pragma unroll
                    for (int fc = 0; fc < 4; ++fc)
#pragma unroll
                        for (int r = 0; r < 4; ++r)
                            if ((kt * 64 + fc * 16 + hi * 4 + r) > qabs) s[half][fc][r] = -1e30f;
                }
                // online softmax with defer-max (T13; THR = 8*log2e in log2 domain)
                float pm = s[half][0][0];
#pragma unroll
                for (int fc = 0; fc < 4; ++fc)
#pragma unroll
                    for (int r = 0; r < 4; ++r) pm = fmaxf(pm, s[half][fc][r]);
                pm = fmaxf(pm, __shfl_xor(pm, 16));
                pm = fmaxf(pm, __shfl_xor(pm, 32));
                if (!__all(pm - mrun[half] <= 11.541560327111708f)) {
                    float mn = fmaxf(mrun[half], pm);
                    float fr = exp2f(mrun[half] - mn);
                    mrun[half] = mn;
                    lrun[half] *= fr;
#pragma unroll
                    for (int dhf = 0; dhf < 8; ++dhf)
#pragma unroll
                        for (int r = 0; r < 4; ++r) acc[half][dhf][r] *= fr;
                }
                float ls = 0.f;
#pragma unroll
                for (int fc = 0; fc < 4; ++fc)
#pragma unroll
                    for (int r = 0; r < 4; ++r) {
                        float e = exp2f(s[half][fc][r] - mrun[half]);
                        s[half][fc][r] = e;
                        ls += e;
                    }
                ls += __shfl_xor(ls, 16);
                ls += __shfl_xor(ls, 32);
                lrun[half] += ls;
                // P -> LDS: row q = half*16+lr (128 B/row -> half block at 2048 B)
#pragma unroll
                for (int fc = 0; fc < 4; ++fc) {
                    u32x2 pk;
                    pk.x = (u32)f2b(s[half][fc][0]) | ((u32)f2b(s[half][fc][1]) << 16);
                    pk.y = (u32)f2b(s[half][fc][2]) | ((u32)f2b(s[half][fc][3]) << 16);
                    int byt = (half * 2048 + lr * 128 + fc * 32 + hi * 8) ^ ((lr & 7) << 4);
                    *(u32x2*)((char*)Pw + byt) = pk;
                }
            }
            asm volatile("s_waitcnt lgkmcnt(0)" ::: "memory");
            // O^T += V^T P^T; each vf read shared by both halves
            __builtin_amdgcn_s_setprio(1);
#pragma unroll
            for (int kk2 = 0; kk2 < 2; ++kk2) {
                bf16x8 pf0 = *(const bf16x8*)((const char*)Pw +
                    ((lr * 128 + kk2 * 64 + hi * 16) ^ ((lr & 7) << 4)));
                bf16x8 pf1 = *(const bf16x8*)((const char*)Pw +
                    ((2048 + lr * 128 + kk2 * 64 + hi * 16) ^ ((lr & 7) << 4)));
#pragma unroll
                for (int dhf = 0; dhf < 8; ++dhf) {
                    int dh = dhf * 16 + lr;
                    int bytv = (dh * 128 + (kk2 * 32 + 8 * hi) * 2) ^ ((dh & 7) << 4);
                    bf16x8 vf = *(const bf16x8*)((const char*)Vs + bytv);
                    acc[0][dhf] = mfma16(vf, pf0, acc[0][dhf]);
                    acc[1][dhf] = mfma16(vf, pf1, acc[1][dhf]);
                }
            }
            __builtin_amdgcn_s_setprio(0);
            __syncthreads();   // drains vmcnt -> prefetched tile ready; buf[cur] reads retired
            cur ^= 1;
        }
        // epilogue
#pragma unroll
        for (int half = 0; half < 2; ++half) {
            float inv = 1.0f / lrun[half];
            int qrow = q0 + w * 32 + half * 16 + lr;
#pragma unroll
            for (int dhf = 0; dhf < 8; ++dhf) {
                ushort4 o;
                o.x = f2b(acc[half][dhf][0] * inv); o.y = f2b(acc[half][dhf][1] * inv);
                o.z = f2b(acc[half][dhf][2] * inv); o.w = f2b(acc[half][dhf][3] * inv);
                *(ushort4*)(ab + (size_t)(b * 2048 + qrow) * 4096 + h * 128 + dhf * 16 + hi * 4) = o;
            }
        }
    };

    process(15 - blockIdx.x);   // long tile first
    __syncthreads();
    process(blockIdx.x);
}

// ---------------------------------------------------------------- launch
extern "C" void kernel_launch(void* const* d_in, const int* in_sizes, int n_in,
                              void* d_out, int out_size, void* d_ws, size_t ws_size,
                              hipStream_t stream) {
    (void)in_sizes; (void)n_in; (void)out_size; (void)ws_size;
    const float* x  = (const float*)d_in[0];
    // d_in[1] = mask: exact causal tril(0 / -1e9) — handled analytically in attn_kernel
    const float* wq = (const float*)d_in[2];
    const float* wk = (const float*)d_in[3];
    const float* wv = (const float*)d_in[4];
    const float* wo = (const float*)d_in[5];

    char* ws = (char*)d_ws;
    u16* xb  = (u16*)(ws + 0);                       // 32 MiB; reused as ab after QKV GEMM
    u16* fBt = (u16*)(ws + 33554432);                // 48 MiB fused [wq^T; wk^T; wv^T]
    u16* qkv = (u16*)(ws + 83886080);                // 48 MiB [4096][6144]
    u16* vt  = (u16*)(ws + 134217728);               //  8 MiB -> total 142 MiB
    u16* ab  = xb;
    u16* wob = fBt;                                  // reuse fBt region after QKV GEMM

    float* out0 = (float*)d_out;
    float* outk = out0 + 16777216;
    float* outv = out0 + 33554432;

    // merged convx (16384) + tconv3 (6144): outputs are exactly the QKV GEMM's operands
    pre_kernel<<<22528, 256, 0, stream>>>(x, wq, wk, wv, xb, fBt);

    // fused QKV projection: 128x128 tiles, 1536 blocks = 3 rounds at 2/CU (measured best)
    gemm128_bf16_kernel<<<1536, 256, 0, stream>>>(xb, fBt, qkv, 6144, 4096, 32);

    // merged RoPE (q pre-scaled by SC*log2e) + V-transpose + tconv(wo) — all post-GEMM
    postproc_kernel<<<46080, 256, 0, stream>>>(qkv, outk, vt, outv, wo, wob);

    attn_kernel<<<dim3(8, 32, 2), 256, 0, stream>>>(qkv, vt, ab);

    // output projection: 128x128 tiles, grid 32x32 = 1024 blocks = 2 rounds at 2/CU
    gemm128_f32_kernel<<<1024, 256, 0, stream>>>(ab, wob, out0, 4096, 4096, 32);
}

// Round 20
// 560.027 us; speedup vs baseline: 1.0267x; 1.0267x over previous
//
#include <hip/hip_runtime.h>

typedef unsigned short u16;
typedef unsigned int u32;
typedef float f32x4 __attribute__((ext_vector_type(4)));
typedef u32 u32x2 __attribute__((ext_vector_type(2)));
typedef __bf16 bf16x8 __attribute__((ext_vector_type(8)));

#define DEV __device__ __forceinline__

DEV u16 f2b(float f) {
    union { float f; u32 u; } v; v.f = f;
    u32 r = v.u + 0x7fffu + ((v.u >> 16) & 1u);   // RNE
    return (u16)(r >> 16);
}
DEV float b2f(u16 b) {
    union { u32 u; float f; } v; v.u = ((u32)b) << 16;
    return v.f;
}

// global -> LDS direct (16B/lane). LDS dest must be wave-uniform base; HW adds lane*16.
DEV void gload16(const void* g, void* l) {
    __builtin_amdgcn_global_load_lds((const __attribute__((address_space(1))) void*)g,
                                     (__attribute__((address_space(3))) void*)l, 16, 0, 0);
}

DEV f32x4 mfma16(bf16x8 a, bf16x8 b, f32x4 c) {
    return __builtin_amdgcn_mfma_f32_16x16x32_bf16(a, b, c, 0, 0, 0);
}

// -------------- merged pre-GEMM pass: convx ∥ tconv3(wq,wk,wv).
// Both outputs (xb, fBt) are exactly the QKV GEMM's operands — no unrelated working set
// is introduced before the GEMM (r16 lesson: 96 MB of unrelated traffic before the GEMM
// evicted xb/fBt and cost 7% on the GEMM).
__global__ __launch_bounds__(256) void pre_kernel(const float* __restrict__ x,
                                                  const float* __restrict__ wq,
                                                  const float* __restrict__ wk,
                                                  const float* __restrict__ wv,
                                                  u16* __restrict__ xb,
                                                  u16* __restrict__ fBt) {
    int id = blockIdx.x;
    int t = threadIdx.x;
    if (id < 16384) {
        // ---- convx
        size_t i = ((size_t)id * 256 + t) * 4;
        float4 v = *(const float4*)(x + i);
        ushort4 o; o.x = f2b(v.x); o.y = f2b(v.y); o.z = f2b(v.z); o.w = f2b(v.w);
        *(ushort4*)(xb + i) = o;
        return;
    }
    // ---- tconv3: i0 -> (bx = i0 % 96, ky = i0 / 96)
    __shared__ float tile[64][65];
    int i0 = id - 16384;
    int n0 = (i0 % 96) * 64, k0 = (i0 / 96) * 64;
    const float* src; int Ns, nl;
    if (n0 < 4096)      { src = wq; Ns = 4096; nl = n0; }
    else if (n0 < 5120) { src = wk; Ns = 1024; nl = n0 - 4096; }
    else                { src = wv; Ns = 1024; nl = n0 - 5120; }
    int r = t >> 4, c4 = (t & 15) * 4;
#pragma unroll
    for (int i = 0; i < 4; ++i) {
        float4 v = *(const float4*)(src + (size_t)(k0 + i * 16 + r) * Ns + nl + c4);
        tile[i * 16 + r][c4 + 0] = v.x; tile[i * 16 + r][c4 + 1] = v.y;
        tile[i * 16 + r][c4 + 2] = v.z; tile[i * 16 + r][c4 + 3] = v.w;
    }
    __syncthreads();
#pragma unroll
    for (int i = 0; i < 4; ++i) {
        int nn = i * 16 + r;
        ushort4 o;
        o.x = f2b(tile[c4 + 0][nn]); o.y = f2b(tile[c4 + 1][nn]);
        o.z = f2b(tile[c4 + 2][nn]); o.w = f2b(tile[c4 + 3][nn]);
        *(ushort4*)(fBt + (size_t)(n0 + nn) * 4096 + k0 + c4) = o;
    }
}

// ----------------------- 128x128 2-phase GEMM body (r10/r13/r17 measured-best: 43%
// MfmaUtil, 2 independent blocks/CU, LDS 64 KiB; ~90-95% of this data path's LDS-BW
// structural bound. Six geometry/schedule variants (r3-r6, r12, r14) all worse.)
#define GEMM128_BODY                                                                        \
    __shared__ __align__(16) u16 Asb[2][2][64 * 64];                                        \
    __shared__ __align__(16) u16 Bsb[2][2][64 * 64];                                        \
    int t = threadIdx.x;                                                                    \
    int lane = t & 63, w = t >> 6;                                                          \
    int wrM = w >> 1, wcN = w & 1;                                                          \
    int lr = lane & 15, hi = lane >> 4;                                                     \
    int wg = blockIdx.x;                                                                    \
    int swz = (wg & 7) * ((int)gridDim.x >> 3) + (wg >> 3);                                 \
    int bx = swz / gy, by = swz % gy;                                                       \
    int m0 = by * 128, n0 = bx * 128;                                                       \
    int nk = K >> 6;                                                                        \
    auto stageA = [&](int X, int h) {                                                       \
        const u16* src = A + (size_t)(m0 + h * 64) * K + X * 64;                            \
        char* dst = (char*)&Asb[X & 1][h][0];                                               \
        _Pragma("unroll")                                                                   \
        for (int it = 0; it < 2; ++it) {                                                    \
            int c = it * 256 + t;                                                           \
            int row = c >> 3;                                                               \
            int col8 = ((c & 7) ^ (row & 7)) << 3;                                          \
            gload16(src + (size_t)row * K + col8, dst + (it * 256 + (t & ~63)) * 16);       \
        }                                                                                   \
    };                                                                                      \
    auto stageB = [&](int X, int h) {                                                       \
        const u16* src = Bt + (size_t)(n0 + h * 64) * K + X * 64;                           \
        char* dst = (char*)&Bsb[X & 1][h][0];                                               \
        _Pragma("unroll")                                                                   \
        for (int it = 0; it < 2; ++it) {                                                    \
            int c = it * 256 + t;                                                           \
            int row = c >> 3;                                                               \
            int col8 = ((c & 7) ^ (row & 7)) << 3;                                          \
            gload16(src + (size_t)row * K + col8, dst + (it * 256 + (t & ~63)) * 16);       \
        }                                                                                   \
    };                                                                                      \
    stageA(0, 0); stageA(0, 1); stageB(0, 0); stageB(0, 1);                                 \
    stageA(1, 0); stageA(1, 1);                                                             \
    asm volatile("s_waitcnt vmcnt(4)" ::: "memory");                                        \
    __builtin_amdgcn_s_barrier();                                                           \
    f32x4 acc[4][4] = {};                                                                   \
    for (int kt = 0; kt < nk; ++kt) {                                                       \
        __builtin_amdgcn_sched_barrier(0);                                                  \
        int p = kt & 1;                                                                     \
        const char* Ah = (const char*)&Asb[p][wrM][0];                                      \
        const char* Bh = (const char*)&Bsb[p][wcN][0];                                      \
        bool s1 = (kt + 1 < nk), s2 = (kt + 2 < nk);                                        \
        bf16x8 a[4][2], bb[2][2];                                                           \
        _Pragma("unroll")                                                                   \
        for (int mf = 0; mf < 4; ++mf)                                                      \
            _Pragma("unroll")                                                               \
            for (int ks = 0; ks < 2; ++ks) {                                                \
                int row = mf * 16 + lr;                                                     \
                a[mf][ks] = *(const bf16x8*)(Ah + ((row * 128 + ks * 64 + hi * 16) ^ ((row & 7) << 4))); \
            }                                                                               \
        _Pragma("unroll")                                                                   \
        for (int nf = 0; nf < 2; ++nf)                                                      \
            _Pragma("unroll")                                                               \
            for (int ks = 0; ks < 2; ++ks) {                                                \
                int row = nf * 16 + lr;                                                     \
                bb[nf][ks] = *(const bf16x8*)(Bh + ((row * 128 + ks * 64 + hi * 16) ^ ((row & 7) << 4))); \
            }                                                                               \
        if (s1) { stageB(kt + 1, 0); stageB(kt + 1, 1); }                                   \
        __builtin_amdgcn_s_barrier();                                                       \
        __builtin_amdgcn_s_setprio(1);                                                      \
        _Pragma("unroll")                                                                   \
        for (int mf = 0; mf < 4; ++mf)                                                      \
            _Pragma("unroll")                                                               \
            for (int nf = 0; nf < 2; ++nf)                                                  \
                _Pragma("unroll")                                                           \
                for (int ks = 0; ks < 2; ++ks)                                              \
                    acc[mf][nf] = mfma16(a[mf][ks], bb[nf][ks], acc[mf][nf]);               \
        __builtin_amdgcn_s_setprio(0);                                                      \
        __builtin_amdgcn_s_barrier();                                                       \
        _Pragma("unroll")                                                                   \
        for (int nf = 0; nf < 2; ++nf)                                                      \
            _Pragma("unroll")                                                               \
            for (int ks = 0; ks < 2; ++ks) {                                                \
                int row = (nf + 2) * 16 + lr;                                               \
                bb[nf][ks] = *(const bf16x8*)(Bh + ((row * 128 + ks * 64 + hi * 16) ^ ((row & 7) << 4))); \
            }                                                                               \
        if (s2) { stageA(kt + 2, 0); stageA(kt + 2, 1); }                                   \
        __builtin_amdgcn_s_barrier();                                                       \
        __builtin_amdgcn_s_setprio(1);                                                      \
        _Pragma("unroll")                                                                   \
        for (int mf = 0; mf < 4; ++mf)                                                      \
            _Pragma("unroll")                                                               \
            for (int nf = 0; nf < 2; ++nf)                                                  \
                _Pragma("unroll")                                                           \
                for (int ks = 0; ks < 2; ++ks)                                              \
                    acc[mf][nf + 2] = mfma16(a[mf][ks], bb[nf][ks], acc[mf][nf + 2]);       \
        __builtin_amdgcn_s_setprio(0);                                                      \
        if (s2)      asm volatile("s_waitcnt vmcnt(4)" ::: "memory");                       \
        else if (s1) asm volatile("s_waitcnt vmcnt(0)" ::: "memory");                       \
        __builtin_amdgcn_s_barrier();                                                       \
    }

// ------------------- bf16-out 128x128 GEMM (QKV projection)
__global__ __launch_bounds__(256, 2) void gemm128_bf16_kernel(const u16* __restrict__ A,
                                                              const u16* __restrict__ Bt,
                                                              u16* __restrict__ Cb,
                                                              int N, int K, int gy) {
    GEMM128_BODY
#pragma unroll
    for (int mf = 0; mf < 4; ++mf)
#pragma unroll
        for (int nf = 0; nf < 4; ++nf)
#pragma unroll
            for (int r = 0; r < 4; ++r) {
                int m = m0 + wrM * 64 + mf * 16 + hi * 4 + r;
                int n = n0 + wcN * 64 + nf * 16 + lr;
                Cb[(size_t)m * N + n] = f2b(acc[mf][nf][r]);
            }
}

// ------------------- f32-out 128x128 GEMM (WO projection)
__global__ __launch_bounds__(256, 2) void gemm128_f32_kernel(const u16* __restrict__ A,
                                                             const u16* __restrict__ Bt,
                                                             float* __restrict__ Cf,
                                                             int N, int K, int gy) {
    GEMM128_BODY
#pragma unroll
    for (int mf = 0; mf < 4; ++mf)
#pragma unroll
        for (int nf = 0; nf < 4; ++nf)
#pragma unroll
            for (int r = 0; r < 4; ++r) {
                int m = m0 + wrM * 64 + mf * 16 + hi * 4 + r;
                int n = n0 + wcN * 64 + nf * 16 + lr;
                Cf[(size_t)m * N + n] = acc[mf][nf][r];
            }
}

// -------------- merged post-QKV pass: RoPE(q pre-scaled, k + outk f32 x4) ∥ V-transpose
// ∥ tconv(wo). All three run between the QKV GEMM and their consumers (r16 cache lesson).
__global__ __launch_bounds__(256) void postproc_kernel(u16* __restrict__ qkv,
                                                       float* __restrict__ outk,
                                                       u16* __restrict__ vt,
                                                       float* __restrict__ outv,
                                                       const float* __restrict__ wo,
                                                       u16* __restrict__ wob) {
    int id = blockIdx.x;
    int tid = threadIdx.x;
    if (id < 40960) {
        // ---- RoPE: id -> (bx = id%10, row = id/10)
        int row = id / 10;
        int p = (id % 10) * 256 + tid;
        int b = row >> 11, l = row & 2047;
        float freq = exp2f((float)(p & 63) * -0.2076205059304601f);  // 10000^(-i/64)
        float sv, cv; sincosf((float)l * freq, &sv, &cv);
        if (p < 2048) {
            const float SC = 0.08838834764831845f;  // 1/sqrt(128) folded into q
            int h = p >> 6, i = p & 63;
            size_t idx = (size_t)row * 6144 + h * 128 + 2 * i;
            u32 pr = *(const u32*)(qkv + idx);
            float x1 = b2f((u16)(pr & 0xffff)), x2 = b2f((u16)(pr >> 16));
            float o1 = (x1 * cv + x2 * sv) * SC, o2 = (x1 * sv - x2 * cv) * SC;
            *(u32*)(qkv + idx) = (u32)f2b(o1) | ((u32)f2b(o2) << 16);
        } else {
            int kvh = (p >> 6) - 32, i = p & 63;
            size_t idx = (size_t)row * 6144 + 4096 + kvh * 128 + 2 * i;
            u32 pr = *(const u32*)(qkv + idx);
            float x1 = b2f((u16)(pr & 0xffff)), x2 = b2f((u16)(pr >> 16));
            float o1 = x1 * cv + x2 * sv, o2 = x1 * sv - x2 * cv;
            *(u32*)(qkv + idx) = (u32)f2b(o1) | ((u32)f2b(o2) << 16);
#pragma unroll
            for (int r = 0; r < 4; ++r) {
                float2 o; o.x = o1; o.y = o2;
                *(float2*)(outk + ((size_t)((b * 32 + kvh * 4 + r) * 2048) + l) * 128 + 2 * i) = o;
            }
        }
        return;
    }
    __shared__ u16 tile16[64][65];
    __shared__ float tile32[64][65];
    if (id < 41984) {
        // ---- V transpose
        int i0 = id - 40960;
        int l0 = (i0 & 31) * 64, d0 = ((i0 >> 5) & 1) * 64;
        int z = i0 >> 6, b = z >> 3, kvh = z & 7;
        int r = tid >> 4, c4 = (tid & 15) * 4;
#pragma unroll
        for (int i = 0; i < 4; ++i) {
            int l = l0 + i * 16 + r;
            ushort4 v = *(const ushort4*)(qkv + (size_t)(b * 2048 + l) * 6144 + 5120 + kvh * 128 + d0 + c4);
            tile16[i * 16 + r][c4 + 0] = v.x; tile16[i * 16 + r][c4 + 1] = v.y;
            tile16[i * 16 + r][c4 + 2] = v.z; tile16[i * 16 + r][c4 + 3] = v.w;
            float4 f; f.x = b2f(v.x); f.y = b2f(v.y); f.z = b2f(v.z); f.w = b2f(v.w);
#pragma unroll
            for (int rr = 0; rr < 4; ++rr)
                *(float4*)(outv + ((size_t)((b * 32 + kvh * 4 + rr) * 2048) + l) * 128 + d0 + c4) = f;
        }
        __syncthreads();
#pragma unroll
        for (int i = 0; i < 4; ++i) {
            int dn = i * 16 + r;
            ushort4 o;
            o.x = tile16[c4 + 0][dn]; o.y = tile16[c4 + 1][dn];
            o.z = tile16[c4 + 2][dn]; o.w = tile16[c4 + 3][dn];
            *(ushort4*)(vt + (size_t)((b * 8 + kvh) * 128 + d0 + dn) * 2048 + l0 + c4) = o;
        }
    } else {
        // ---- tconv(wo): i1 -> (nx = i1 & 63, ky = i1 >> 6)
        int i1 = id - 41984;
        int n0 = (i1 & 63) * 64, k0 = (i1 >> 6) * 64;
        int r = tid >> 4, c4 = (tid & 15) * 4;
#pragma unroll
        for (int i = 0; i < 4; ++i) {
            float4 v = *(const float4*)(wo + (size_t)(k0 + i * 16 + r) * 4096 + n0 + c4);
            tile32[i * 16 + r][c4 + 0] = v.x; tile32[i * 16 + r][c4 + 1] = v.y;
            tile32[i * 16 + r][c4 + 2] = v.z; tile32[i * 16 + r][c4 + 3] = v.w;
        }
        __syncthreads();
#pragma unroll
        for (int i = 0; i < 4; ++i) {
            int nn = i * 16 + r;
            ushort4 o;
            o.x = f2b(tile32[c4 + 0][nn]); o.y = f2b(tile32[c4 + 1][nn]);
            o.z = f2b(tile32[c4 + 2][nn]); o.w = f2b(tile32[c4 + 3][nn]);
            *(ushort4*)(wob + (size_t)(n0 + nn) * 4096 + k0 + c4) = o;
        }
    }
}

// ---------------------------------------------------------------- flash attention v4.2
// 32 q-rows/wave (two 16-row halves sharing every K/V fragment read); QBLK=128/block,
// grid (8,32,2) = 512 blocks = 2/CU (LDS 80 KB). q pre-scaled; T13 defer-max (THR=8).
// Passed r16-r18 at absmax 0.031; r18 total = session best (561.7 us).
__global__ __launch_bounds__(256, 2) void attn_kernel(const u16* __restrict__ qkv,
                                                      const u16* __restrict__ vt,
                                                      u16* __restrict__ ab) {
    __shared__ __align__(16) u16 Kbuf[2][64 * 128];   // K tile [kv][dh]     32 KB
    __shared__ __align__(16) u16 Vbuf[2][128 * 64];   // V^T tile [dh][kv]   32 KB
    __shared__ __align__(16) u16 Ps[4][32 * 64];      // per-wave P [q=32][kv=64]  16 KB
    int t = threadIdx.x, lane = t & 63, w = t >> 6;
    int lr = lane & 15, hi = lane >> 4;
    int h = blockIdx.y, b = blockIdx.z, kvh = h >> 2;

    const u16* kbase = qkv + (size_t)(b * 2048) * 6144 + 4096 + kvh * 128;
    const u16* vtbase = vt + (size_t)((b * 8 + kvh) * 128) * 2048;

    auto stageKV = [&](int k0, int buf) {
#pragma unroll
        for (int i = 0; i < 4; ++i) {   // K: 64 rows x 128 cols
            int c = i * 256 + t;
            int row = c >> 4;
            int col8 = ((c & 15) ^ (row & 7)) << 3;
            gload16(kbase + (size_t)(k0 + row) * 6144 + col8,
                    (char*)Kbuf[buf] + (i * 256 + (t & ~63)) * 16);
        }
#pragma unroll
        for (int i = 0; i < 4; ++i) {   // V^T: 128 rows x 64 cols
            int c = i * 256 + t;
            int row = c >> 3;
            int col8 = ((c & 7) ^ (row & 7)) << 3;
            gload16(vtbase + (size_t)row * 2048 + k0 + col8,
                    (char*)Vbuf[buf] + (i * 256 + (t & ~63)) * 16);
        }
    };

    auto process = [&](int qblk) {
        int q0 = qblk * 128;
        bf16x8 qf[2][4];
#pragma unroll
        for (int half = 0; half < 2; ++half)
#pragma unroll
            for (int kki = 0; kki < 4; ++kki)
                qf[half][kki] = *(const bf16x8*)(qkv +
                    (size_t)(b * 2048 + q0 + w * 32 + half * 16 + lr) * 6144 + h * 128 +
                    kki * 32 + 8 * hi);
        f32x4 acc[2][8] = {};
        float mrun[2] = {-1e30f, -1e30f}, lrun[2] = {0.f, 0.f};

        int nt = 2 * (qblk + 1);
        stageKV(0, 0);
        __syncthreads();
        int cur = 0;
        for (int kt = 0; kt < nt; ++kt) {
            if (kt + 1 < nt) stageKV((kt + 1) * 64, cur ^ 1);  // prefetch next tile
            __builtin_amdgcn_sched_barrier(0);

            const u16* Ks = Kbuf[cur];
            const u16* Vs = Vbuf[cur];
            // S^T = K Q^T for both halves, sharing each kf read (q pre-scaled by 1/sqrt(d))
            f32x4 s[2][4] = {};
            __builtin_amdgcn_s_setprio(1);
#pragma unroll
            for (int kki = 0; kki < 4; ++kki) {
                bf16x8 kf[4];
#pragma unroll
                for (int fc = 0; fc < 4; ++fc) {
                    int kvr = fc * 16 + lr;
                    int byt = (kvr * 256 + (kki * 32 + 8 * hi) * 2) ^ ((kvr & 7) << 4);
                    kf[fc] = *(const bf16x8*)((const char*)Ks + byt);
                }
#pragma unroll
                for (int fc = 0; fc < 4; ++fc) {
                    s[0][fc] = mfma16(kf[fc], qf[0][kki], s[0][fc]);
                    s[1][fc] = mfma16(kf[fc], qf[1][kki], s[1][fc]);
                }
            }
            __builtin_amdgcn_s_setprio(0);
            int domask = (kt >= nt - 2);
            u16* Pw = Ps[w];
#pragma unroll
            for (int half = 0; half < 2; ++half) {
                int qabs = q0 + w * 32 + half * 16 + lr;
                if (domask) {
#pragma unroll
                    for (int fc = 0; fc < 4; ++fc)
#pragma unroll
                        for (int r = 0; r < 4; ++r)
                            if ((kt * 64 + fc * 16 + hi * 4 + r) > qabs) s[half][fc][r] = -1e30f;
                }
                // online softmax with defer-max (T13, THR=8)
                float pm = s[half][0][0];
#pragma unroll
                for (int fc = 0; fc < 4; ++fc)
#pragma unroll
                    for (int r = 0; r < 4; ++r) pm = fmaxf(pm, s[half][fc][r]);
                pm = fmaxf(pm, __shfl_xor(pm, 16));
                pm = fmaxf(pm, __shfl_xor(pm, 32));
                if (!__all(pm - mrun[half] <= 8.0f)) {
                    float mn = fmaxf(mrun[half], pm);
                    float fr = __expf(mrun[half] - mn);
                    mrun[half] = mn;
                    lrun[half] *= fr;
#pragma unroll
                    for (int dhf = 0; dhf < 8; ++dhf)
#pragma unroll
                        for (int r = 0; r < 4; ++r) acc[half][dhf][r] *= fr;
                }
                float ls = 0.f;
#pragma unroll
                for (int fc = 0; fc < 4; ++fc)
#pragma unroll
                    for (int r = 0; r < 4; ++r) {
                        float e = __expf(s[half][fc][r] - mrun[half]);
                        s[half][fc][r] = e;
                        ls += e;
                    }
                ls += __shfl_xor(ls, 16);
                ls += __shfl_xor(ls, 32);
                lrun[half] += ls;
                // P -> LDS: row q = half*16+lr (128 B/row -> half block at 2048 B)
#pragma unroll
                for (int fc = 0; fc < 4; ++fc) {
                    u32x2 pk;
                    pk.x = (u32)f2b(s[half][fc][0]) | ((u32)f2b(s[half][fc][1]) << 16);
                    pk.y = (u32)f2b(s[half][fc][2]) | ((u32)f2b(s[half][fc][3]) << 16);
                    int byt = (half * 2048 + lr * 128 + fc * 32 + hi * 8) ^ ((lr & 7) << 4);
                    *(u32x2*)((char*)Pw + byt) = pk;
                }
            }
            asm volatile("s_waitcnt lgkmcnt(0)" ::: "memory");
            // O^T += V^T P^T; each vf read shared by both halves
            __builtin_amdgcn_s_setprio(1);
#pragma unroll
            for (int kk2 = 0; kk2 < 2; ++kk2) {
                bf16x8 pf0 = *(const bf16x8*)((const char*)Pw +
                    ((lr * 128 + kk2 * 64 + hi * 16) ^ ((lr & 7) << 4)));
                bf16x8 pf1 = *(const bf16x8*)((const char*)Pw +
                    ((2048 + lr * 128 + kk2 * 64 + hi * 16) ^ ((lr & 7) << 4)));
#pragma unroll
                for (int dhf = 0; dhf < 8; ++dhf) {
                    int dh = dhf * 16 + lr;
                    int bytv = (dh * 128 + (kk2 * 32 + 8 * hi) * 2) ^ ((dh & 7) << 4);
                    bf16x8 vf = *(const bf16x8*)((const char*)Vs + bytv);
                    acc[0][dhf] = mfma16(vf, pf0, acc[0][dhf]);
                    acc[1][dhf] = mfma16(vf, pf1, acc[1][dhf]);
                }
            }
            __builtin_amdgcn_s_setprio(0);
            __syncthreads();   // drains vmcnt -> prefetched tile ready; buf[cur] reads retired
            cur ^= 1;
        }
        // epilogue
#pragma unroll
        for (int half = 0; half < 2; ++half) {
            float inv = 1.0f / lrun[half];
            int qrow = q0 + w * 32 + half * 16 + lr;
#pragma unroll
            for (int dhf = 0; dhf < 8; ++dhf) {
                ushort4 o;
                o.x = f2b(acc[half][dhf][0] * inv); o.y = f2b(acc[half][dhf][1] * inv);
                o.z = f2b(acc[half][dhf][2] * inv); o.w = f2b(acc[half][dhf][3] * inv);
                *(ushort4*)(ab + (size_t)(b * 2048 + qrow) * 4096 + h * 128 + dhf * 16 + hi * 4) = o;
            }
        }
    };

    process(15 - blockIdx.x);   // long tile first
    __syncthreads();
    process(blockIdx.x);
}

// ---------------------------------------------------------------- launch
extern "C" void kernel_launch(void* const* d_in, const int* in_sizes, int n_in,
                              void* d_out, int out_size, void* d_ws, size_t ws_size,
                              hipStream_t stream) {
    (void)in_sizes; (void)n_in; (void)out_size; (void)ws_size;
    const float* x  = (const float*)d_in[0];
    // d_in[1] = mask: exact causal tril(0 / -1e9) — handled analytically in attn_kernel
    const float* wq = (const float*)d_in[2];
    const float* wk = (const float*)d_in[3];
    const float* wv = (const float*)d_in[4];
    const float* wo = (const float*)d_in[5];

    char* ws = (char*)d_ws;
    u16* xb  = (u16*)(ws + 0);                       // 32 MiB; reused as ab after QKV GEMM
    u16* fBt = (u16*)(ws + 33554432);                // 48 MiB fused [wq^T; wk^T; wv^T]
    u16* qkv = (u16*)(ws + 83886080);                // 48 MiB [4096][6144]
    u16* vt  = (u16*)(ws + 134217728);               //  8 MiB -> total 142 MiB
    u16* ab  = xb;
    u16* wob = fBt;                                  // reuse fBt region after QKV GEMM

    float* out0 = (float*)d_out;
    float* outk = out0 + 16777216;
    float* outv = out0 + 33554432;

    // merged convx (16384) + tconv3 (6144): outputs are exactly the QKV GEMM's operands
    pre_kernel<<<22528, 256, 0, stream>>>(x, wq, wk, wv, xb, fBt);

    // fused QKV projection: 128x128 tiles, 1536 blocks = 3 rounds at 2/CU (measured best)
    gemm128_bf16_kernel<<<1536, 256, 0, stream>>>(xb, fBt, qkv, 6144, 4096, 32);

    // merged RoPE (q pre-scaled) + V-transpose + tconv(wo) — all post-GEMM (r16 lesson)
    postproc_kernel<<<46080, 256, 0, stream>>>(qkv, outk, vt, outv, wo, wob);

    attn_kernel<<<dim3(8, 32, 2), 256, 0, stream>>>(qkv, vt, ab);

    // output projection: 128x128 tiles, grid 32x32 = 1024 blocks = 2 rounds at 2/CU
    gemm128_f32_kernel<<<1024, 256, 0, stream>>>(ab, wob, out0, 4096, 4096, 32);
}